// Round 7
// baseline (54.751 us; speedup 1.0000x reference)
//
#include <hip/hip_runtime.h>

#define NSEG 16384
#define EPS  1e-12f

// windowed lower_bound(map, b) with full-range fallback (exact always)
__device__ __forceinline__ int wlb(const int* __restrict__ map, int n, int b) {
    int est = b << 10;  // n/NSEG == 1024
    int wlo = est - 20000; if (wlo < 0) wlo = 0;
    int whi = est + 20000; if (whi > n) whi = n;
    int lo = wlo, hi = whi;
    while (lo < hi) { int mid = (lo + hi) >> 1; if (map[mid] < b) lo = mid + 1; else hi = mid; }
    bool bad = (lo == wlo && wlo > 0 && map[wlo - 1] >= b) ||
               (lo == whi && whi < n && map[whi] < b);
    if (bad) {
        lo = 0; hi = n;
        while (lo < hi) { int mid = (lo + hi) >> 1; if (map[mid] < b) lo = mid + 1; else hi = mid; }
    }
    return lo;
}

// ---------- DPP wave64 sum: row_shr 1/2/4/8 + row_bcast 15/31; total in lane 63 ----------
#define DPP_ADD_IMPL(CTRL)                                                     \
    __device__ __forceinline__ float dpp_add_##CTRL(float x) {                 \
        int y = __builtin_amdgcn_update_dpp(0, __float_as_int(x), CTRL,        \
                                            0xf, 0xf, true);                   \
        return x + __int_as_float(y);                                          \
    }
DPP_ADD_IMPL(0x111)  // row_shr:1
DPP_ADD_IMPL(0x112)  // row_shr:2
DPP_ADD_IMPL(0x114)  // row_shr:4
DPP_ADD_IMPL(0x118)  // row_shr:8
DPP_ADD_IMPL(0x142)  // row_bcast:15
DPP_ADD_IMPL(0x143)  // row_bcast:31

#define DPPRED3(x, y, z)                                                       \
    do {                                                                       \
        x = dpp_add_0x111(x); y = dpp_add_0x111(y); z = dpp_add_0x111(z);      \
        x = dpp_add_0x112(x); y = dpp_add_0x112(y); z = dpp_add_0x112(z);      \
        x = dpp_add_0x114(x); y = dpp_add_0x114(y); z = dpp_add_0x114(z);      \
        x = dpp_add_0x118(x); y = dpp_add_0x118(y); z = dpp_add_0x118(z);      \
        x = dpp_add_0x142(x); y = dpp_add_0x142(y); z = dpp_add_0x142(z);      \
        x = dpp_add_0x143(x); y = dpp_add_0x143(y); z = dpp_add_0x143(z);      \
    } while (0)

// issue one chunk's 8 independent dwordx4 loads
#define LOADC(P, T, CIDX)                                                      \
    do {                                                                       \
        const int vb_ = (CIDX) << 8;                                           \
        _Pragma("unroll")                                                      \
        for (int k_ = 0; k_ < 4; ++k_) P[k_] = p4[vb_ + k_ * 64 + lane];       \
        _Pragma("unroll")                                                      \
        for (int k_ = 0; k_ < 4; ++k_) T[k_] = t4[vb_ + k_ * 64 + lane];       \
    } while (0)

// per-element masked accumulate for boundary groups
#define COLX(pe, te, eidx)                                                     \
    { const float px_ = (pe), tx_ = (te);                                      \
      const float cxx_ = px_ * px_, cyy_ = tx_ * tx_, cxy_ = px_ * tx_;        \
      const bool i0_ = (eidx) < b1_;                                           \
      const bool i2_ = (eidx) >= b2_;                                          \
      q0 += i0_ ? cxx_ : 0.f; r0 += i0_ ? cyy_ : 0.f; u0 += i0_ ? cxy_ : 0.f;  \
      q2 += i2_ ? cxx_ : 0.f; r2 += i2_ ? cyy_ : 0.f; u2 += i2_ ? cxy_ : 0.f;  \
      const bool i1_ = !i0_ && !i2_;                                           \
      q1 += i1_ ? cxx_ : 0.f; r1 += i1_ ? cyy_ : 0.f; u1 += i1_ ? cxy_ : 0.f; }

// route + reduce + flush one 1024-elem chunk. Slot-0 writes carry the segment's
// total slot count in .w  (= ((end-1)>>10) - CIDX + 1, in {1,2,3}) so the
// finalize kernel needs no global start[] and never reads stale wb slots.
#define DO_CHUNK(P, T, CIDX)                                                   \
    do {                                                                       \
        const int hb_ = (CIDX) << 10;                                          \
        const unsigned long long mm_ = __ballot(sv <= hb_);                    \
        const int kk_ = 63 - __builtin_clzll(mm_);                             \
        const int mh_ = base_id + kk_;                                         \
        const int sA_ = __builtin_amdgcn_readlane(sv, kk_);                    \
        const int k1_ = kk_ + 1 > 63 ? 63 : kk_ + 1;                           \
        const int k2_ = kk_ + 2 > 63 ? 63 : kk_ + 2;                           \
        const int k3_ = kk_ + 3 > 63 ? 63 : kk_ + 3;                           \
        const int b1_ = __builtin_amdgcn_readlane(sv, k1_);                    \
        const int b2_ = __builtin_amdgcn_readlane(sv, k2_);                    \
        const int b3_ = __builtin_amdgcn_readlane(sv, k3_);                    \
        float q0=0,r0=0,u0=0, q1=0,r1=0,u1=0, q2=0,r2=0,u2=0;                  \
        _Pragma("unroll")                                                      \
        for (int g_ = 0; g_ < 4; ++g_) {                                       \
            const float4 pv = P[g_], tv = T[g_];                               \
            const int G_ = hb_ + g_ * 256, Ge_ = G_ + 256;                     \
            if (Ge_ <= b1_) {                                                  \
                q0 += pv.x*pv.x + pv.y*pv.y + pv.z*pv.z + pv.w*pv.w;           \
                r0 += tv.x*tv.x + tv.y*tv.y + tv.z*tv.z + tv.w*tv.w;           \
                u0 += pv.x*tv.x + pv.y*tv.y + pv.z*tv.z + pv.w*tv.w;           \
            } else if (G_ >= b1_ && Ge_ <= b2_) {                              \
                q1 += pv.x*pv.x + pv.y*pv.y + pv.z*pv.z + pv.w*pv.w;           \
                r1 += tv.x*tv.x + tv.y*tv.y + tv.z*tv.z + tv.w*tv.w;           \
                u1 += pv.x*tv.x + pv.y*tv.y + pv.z*tv.z + pv.w*tv.w;           \
            } else if (G_ >= b2_) {                                            \
                q2 += pv.x*pv.x + pv.y*pv.y + pv.z*pv.z + pv.w*pv.w;           \
                r2 += tv.x*tv.x + tv.y*tv.y + tv.z*tv.z + tv.w*tv.w;           \
                u2 += pv.x*tv.x + pv.y*tv.y + pv.z*tv.z + pv.w*tv.w;           \
            } else {                                                           \
                const int e0_ = hb_ + (g_ * 64 + lane) * 4;                    \
                COLX(pv.x, tv.x, e0_ + 0)                                      \
                COLX(pv.y, tv.y, e0_ + 1)                                      \
                COLX(pv.z, tv.z, e0_ + 2)                                      \
                COLX(pv.w, tv.w, e0_ + 3)                                      \
            }                                                                  \
        }                                                                      \
        const int nloc_ = (b1_ < hb_ + 1024) + (b2_ < hb_ + 1024);             \
        DPPRED3(q0, r0, u0);                                                   \
        if (nloc_ >= 1) DPPRED3(q1, r1, u1);                                   \
        if (nloc_ >= 2) DPPRED3(q2, r2, u2);                                   \
        if (lane == 63) {                                                      \
            const int slot0_ = (CIDX) - (sA_ >> 10);                           \
            const float w0_ = (slot0_ == 0)                                    \
                ? (float)(((b1_ - 1) >> 10) - (CIDX) + 1) : 0.0f;              \
            wb[mh_ * 3 + slot0_] = make_float4(q0, r0, u0, w0_);               \
            if (nloc_ >= 1) wb[(mh_ + 1) * 3] = make_float4(q1, r1, u1,        \
                (float)(((b2_ - 1) >> 10) - (CIDX) + 1));                      \
            if (nloc_ >= 2) wb[(mh_ + 2) * 3] = make_float4(q2, r2, u2,        \
                (float)(((b3_ - 1) >> 10) - (CIDX) + 1));                      \
        }                                                                      \
    } while (0)

// ---------- K1: stream + in-block LDS bsearch prologue, 4 chunks/wave ----------
__global__ __launch_bounds__(256) void seg_main(const float4* __restrict__ p4,
                                                const float4* __restrict__ t4,
                                                const int* __restrict__ map,
                                                float4* __restrict__ wb,
                                                int* __restrict__ ticket, int n) {
    const int lane = threadIdx.x & 63;
    const int wid  = threadIdx.x >> 6;
    const int wv   = (blockIdx.x << 2) + wid;   // 0..4095
    const int c0   = wv << 2;                   // first of 4 chunks
    const int base_id = c0 - 20;

    // data loads FIRST: 32 independent dwordx4 in flight before the search
    float4 PA[4], TA[4], PB[4], TB[4];
    LOADC(PA, TA, c0);
    LOADC(PB, TB, c0 + 1);

    // block-level windowed binary search into LDS (overlaps data-load latency)
    __shared__ int lds_start[128];
    if (threadIdx.x < 128) {
        int id = (blockIdx.x << 4) - 32 + threadIdx.x;
        id = id < 0 ? 0 : (id > NSEG ? NSEG : id);
        lds_start[threadIdx.x] = wlb(map, n, id);
    }
    if (blockIdx.x == 0 && threadIdx.x == 0) *ticket = 0;  // reset for fin_fused
    __syncthreads();
    // wave's 64-id window: id = c0 - 20 + lane  (same semantics as global gather)
    const int sv = lds_start[(wid << 2) + 12 + lane];

    DO_CHUNK(PA, TA, c0);          // next chunks' loads stay in flight
    LOADC(PA, TA, c0 + 2);
    DO_CHUNK(PB, TB, c0 + 1);
    LOADC(PB, TB, c0 + 3);
    DO_CHUNK(PA, TA, c0 + 2);
    DO_CHUNK(PB, TB, c0 + 3);
}

// ---------- K2: fused finalize: cosine per seg, block partials, ticketed sum ----------
__global__ __launch_bounds__(256) void fin_fused(const float4* __restrict__ wb,
                                                 float* __restrict__ part,
                                                 int* __restrict__ ticket,
                                                 float* __restrict__ out) {
    const int s = blockIdx.x * 256 + threadIdx.x;  // 64 blocks x 256 = 16384
    float4 v = wb[s * 3];
    const int ns = (int)v.w;                       // live slots for this seg
    if (ns >= 2) { float4 u = wb[s * 3 + 1]; v.x += u.x; v.y += u.y; v.z += u.z; }
    if (ns >= 3) { float4 u = wb[s * 3 + 2]; v.x += u.x; v.y += u.y; v.z += u.z; }
    float local = 1.0f - v.z / fmaxf(sqrtf(v.x) * sqrtf(v.y), EPS);

    #pragma unroll
    for (int off = 32; off > 0; off >>= 1) local += __shfl_down(local, off);
    __shared__ float ws4[4];
    __shared__ int is_last;
    if ((threadIdx.x & 63) == 0) ws4[threadIdx.x >> 6] = local;
    __syncthreads();
    if (threadIdx.x == 0) {
        part[blockIdx.x] = ws4[0] + ws4[1] + ws4[2] + ws4[3];
        __threadfence();                            // release partial
        is_last = (atomicAdd(ticket, 1) == 63);
    }
    __syncthreads();
    if (is_last && threadIdx.x < 64) {
        __threadfence();                            // acquire
        // atomic-read (RMW at device coherence point; safe across XCDs)
        float pv = atomicAdd(&part[threadIdx.x], 0.0f);
        #pragma unroll
        for (int off = 32; off > 0; off >>= 1) pv += __shfl_down(pv, off);
        if (threadIdx.x == 0) out[0] = pv / (float)NSEG;  // fixed-order: deterministic
    }
}

extern "C" void kernel_launch(void* const* d_in, const int* in_sizes, int n_in,
                              void* d_out, int out_size, void* d_ws, size_t ws_size,
                              hipStream_t stream) {
    const float4* p = (const float4*)d_in[0];
    const float4* t = (const float4*)d_in[1];
    const int*    s = (const int*)d_in[2];
    const int n = in_sizes[0];

    // workspace layout
    float4* wb     = (float4*)d_ws;                          // 16384*3*16 = 768 KB
    float*  part   = (float*)((char*)d_ws + 786432);         // 64 floats
    int*    ticket = (int*)((char*)d_ws + 786432 + 256);     // 1 int

    seg_main<<<1024, 256, 0, stream>>>(p, t, s, wb, ticket, n);
    fin_fused<<<64, 256, 0, stream>>>(wb, part, ticket, (float*)d_out);
}

// Round 8
// 38.130 us; speedup vs baseline: 1.4359x; 1.4359x over previous
//
#include <hip/hip_runtime.h>

#define NSEG 16384
#define EPS  1e-12f

// ---------- K1: start[b] = lower_bound(map, b) (windowed + fallback) ----------
__global__ void bsearch_kernel(const int* __restrict__ map,
                               int* __restrict__ start, int n) {
    int b = blockIdx.x * blockDim.x + threadIdx.x;
    if (b > NSEG) return;
    int est = b << 10;  // n/NSEG == 1024
    int wlo = est - 20000; if (wlo < 0) wlo = 0;
    int whi = est + 20000; if (whi > n) whi = n;
    int lo = wlo, hi = whi;
    while (lo < hi) { int mid = (lo + hi) >> 1; if (map[mid] < b) lo = mid + 1; else hi = mid; }
    bool bad = (lo == wlo && wlo > 0 && map[wlo - 1] >= b) ||
               (lo == whi && whi < n && map[whi] < b);
    if (bad) {
        lo = 0; hi = n;
        while (lo < hi) { int mid = (lo + hi) >> 1; if (map[mid] < b) lo = mid + 1; else hi = mid; }
    }
    start[b] = lo;
}

// ---------- DPP wave64 sum: row_shr 1/2/4/8 + row_bcast 15/31; total in lane 63 ----------
#define DPP_ADD_IMPL(CTRL)                                                     \
    __device__ __forceinline__ float dpp_add_##CTRL(float x) {                 \
        int y = __builtin_amdgcn_update_dpp(0, __float_as_int(x), CTRL,        \
                                            0xf, 0xf, true);                   \
        return x + __int_as_float(y);                                          \
    }
DPP_ADD_IMPL(0x111)  // row_shr:1
DPP_ADD_IMPL(0x112)  // row_shr:2
DPP_ADD_IMPL(0x114)  // row_shr:4
DPP_ADD_IMPL(0x118)  // row_shr:8
DPP_ADD_IMPL(0x142)  // row_bcast:15
DPP_ADD_IMPL(0x143)  // row_bcast:31

#define DPPRED3(x, y, z)                                                       \
    do {                                                                       \
        x = dpp_add_0x111(x); y = dpp_add_0x111(y); z = dpp_add_0x111(z);      \
        x = dpp_add_0x112(x); y = dpp_add_0x112(y); z = dpp_add_0x112(z);      \
        x = dpp_add_0x114(x); y = dpp_add_0x114(y); z = dpp_add_0x114(z);      \
        x = dpp_add_0x118(x); y = dpp_add_0x118(y); z = dpp_add_0x118(z);      \
        x = dpp_add_0x142(x); y = dpp_add_0x142(y); z = dpp_add_0x142(z);      \
        x = dpp_add_0x143(x); y = dpp_add_0x143(y); z = dpp_add_0x143(z);      \
    } while (0)

// issue one chunk's 8 independent dwordx4 loads
#define LOADC(P, T, CIDX)                                                      \
    do {                                                                       \
        const int vb_ = (CIDX) << 8;                                           \
        _Pragma("unroll")                                                      \
        for (int k_ = 0; k_ < 4; ++k_) P[k_] = p4[vb_ + k_ * 64 + lane];       \
        _Pragma("unroll")                                                      \
        for (int k_ = 0; k_ < 4; ++k_) T[k_] = t4[vb_ + k_ * 64 + lane];       \
    } while (0)

// per-element masked accumulate for boundary groups
#define COLX(pe, te, eidx)                                                     \
    { const float px_ = (pe), tx_ = (te);                                      \
      const float cxx_ = px_ * px_, cyy_ = tx_ * tx_, cxy_ = px_ * tx_;        \
      const bool i0_ = (eidx) < b1_;                                           \
      const bool i2_ = (eidx) >= b2_;                                          \
      q0 += i0_ ? cxx_ : 0.f; r0 += i0_ ? cyy_ : 0.f; u0 += i0_ ? cxy_ : 0.f;  \
      q2 += i2_ ? cxx_ : 0.f; r2 += i2_ ? cyy_ : 0.f; u2 += i2_ ? cxy_ : 0.f;  \
      const bool i1_ = !i0_ && !i2_;                                           \
      q1 += i1_ ? cxx_ : 0.f; r1 += i1_ ? cyy_ : 0.f; u1 += i1_ ? cxy_ : 0.f; }

// route + reduce + flush one 1024-elem chunk. Slot-0 writes carry the segment's
// total slot count in .w (= ((end-1)>>10) - start_chunk + 1, in {1,2,3}) so the
// finalize kernel needs no global start[] and never reads stale wb slots.
// (Every segment is non-empty at N/B=1024, so slot 0 is rewritten each launch.)
#define DO_CHUNK(P, T, CIDX)                                                   \
    do {                                                                       \
        const int hb_ = (CIDX) << 10;                                          \
        const unsigned long long mm_ = __ballot(sv <= hb_);                    \
        const int kk_ = 63 - __builtin_clzll(mm_);                             \
        const int mh_ = base_id + kk_;                                         \
        const int sA_ = __builtin_amdgcn_readlane(sv, kk_);                    \
        const int k1_ = kk_ + 1 > 63 ? 63 : kk_ + 1;                           \
        const int k2_ = kk_ + 2 > 63 ? 63 : kk_ + 2;                           \
        const int k3_ = kk_ + 3 > 63 ? 63 : kk_ + 3;                           \
        const int b1_ = __builtin_amdgcn_readlane(sv, k1_);                    \
        const int b2_ = __builtin_amdgcn_readlane(sv, k2_);                    \
        const int b3_ = __builtin_amdgcn_readlane(sv, k3_);                    \
        float q0=0,r0=0,u0=0, q1=0,r1=0,u1=0, q2=0,r2=0,u2=0;                  \
        _Pragma("unroll")                                                      \
        for (int g_ = 0; g_ < 4; ++g_) {                                       \
            const float4 pv = P[g_], tv = T[g_];                               \
            const int G_ = hb_ + g_ * 256, Ge_ = G_ + 256;                     \
            if (Ge_ <= b1_) {                                                  \
                q0 += pv.x*pv.x + pv.y*pv.y + pv.z*pv.z + pv.w*pv.w;           \
                r0 += tv.x*tv.x + tv.y*tv.y + tv.z*tv.z + tv.w*tv.w;           \
                u0 += pv.x*tv.x + pv.y*tv.y + pv.z*tv.z + pv.w*tv.w;           \
            } else if (G_ >= b1_ && Ge_ <= b2_) {                              \
                q1 += pv.x*pv.x + pv.y*pv.y + pv.z*pv.z + pv.w*pv.w;           \
                r1 += tv.x*tv.x + tv.y*tv.y + tv.z*tv.z + tv.w*tv.w;           \
                u1 += pv.x*tv.x + pv.y*tv.y + pv.z*tv.z + pv.w*tv.w;           \
            } else if (G_ >= b2_) {                                            \
                q2 += pv.x*pv.x + pv.y*pv.y + pv.z*pv.z + pv.w*pv.w;           \
                r2 += tv.x*tv.x + tv.y*tv.y + tv.z*tv.z + tv.w*tv.w;           \
                u2 += pv.x*tv.x + pv.y*tv.y + pv.z*tv.z + pv.w*tv.w;           \
            } else {                                                           \
                const int e0_ = hb_ + (g_ * 64 + lane) * 4;                    \
                COLX(pv.x, tv.x, e0_ + 0)                                      \
                COLX(pv.y, tv.y, e0_ + 1)                                      \
                COLX(pv.z, tv.z, e0_ + 2)                                      \
                COLX(pv.w, tv.w, e0_ + 3)                                      \
            }                                                                  \
        }                                                                      \
        const int nloc_ = (b1_ < hb_ + 1024) + (b2_ < hb_ + 1024);             \
        DPPRED3(q0, r0, u0);                                                   \
        if (nloc_ >= 1) DPPRED3(q1, r1, u1);                                   \
        if (nloc_ >= 2) DPPRED3(q2, r2, u2);                                   \
        if (lane == 63) {                                                      \
            const int slot0_ = (CIDX) - (sA_ >> 10);                           \
            const float w0_ = (slot0_ == 0)                                    \
                ? (float)(((b1_ - 1) >> 10) - (CIDX) + 1) : 0.0f;              \
            wb[mh_ * 3 + slot0_] = make_float4(q0, r0, u0, w0_);               \
            if (nloc_ >= 1) wb[(mh_ + 1) * 3] = make_float4(q1, r1, u1,        \
                (float)(((b2_ - 1) >> 10) - (CIDX) + 1));                      \
            if (nloc_ >= 2) wb[(mh_ + 2) * 3] = make_float4(q2, r2, u2,        \
                (float)(((b3_ - 1) >> 10) - (CIDX) + 1));                      \
        }                                                                      \
    } while (0)

// ---------- K2: 4096 waves x 4 pipelined 1024-elem chunks ----------
__global__ __launch_bounds__(256) void seg_main(const float4* __restrict__ p4,
                                                const float4* __restrict__ t4,
                                                const int* __restrict__ start,
                                                float4* __restrict__ wb,
                                                int* __restrict__ ticket) {
    const int lane = threadIdx.x & 63;
    const int wv   = (blockIdx.x << 2) + (threadIdx.x >> 6);  // 0..4095
    const int c0   = wv << 2;                                 // first of 4 chunks

    // one meta gather (64 consecutive ints) serves all 4 chunks
    const int base_id = c0 - 20;
    int gidx = base_id + lane;
    gidx = gidx < 0 ? 0 : (gidx > NSEG ? NSEG : gidx);
    const int sv = start[gidx];

    if (blockIdx.x == 0 && threadIdx.x == 0) *ticket = 0;  // reset for fin_fused

    float4 PA[4], TA[4], PB[4], TB[4];
    LOADC(PA, TA, c0);
    LOADC(PB, TB, c0 + 1);

    DO_CHUNK(PA, TA, c0);          // next chunks' loads stay in flight
    LOADC(PA, TA, c0 + 2);
    DO_CHUNK(PB, TB, c0 + 1);
    LOADC(PB, TB, c0 + 3);
    DO_CHUNK(PA, TA, c0 + 2);
    DO_CHUNK(PB, TB, c0 + 3);
}

// ---------- K3: fused finalize: cosine per seg, block partials, ticketed sum ----------
__global__ __launch_bounds__(256) void fin_fused(const float4* __restrict__ wb,
                                                 float* __restrict__ part,
                                                 int* __restrict__ ticket,
                                                 float* __restrict__ out) {
    const int s = blockIdx.x * 256 + threadIdx.x;  // 64 blocks x 256 = 16384
    float4 v = wb[s * 3];
    const int ns = (int)v.w;                       // live slots for this seg
    if (ns >= 2) { float4 u = wb[s * 3 + 1]; v.x += u.x; v.y += u.y; v.z += u.z; }
    if (ns >= 3) { float4 u = wb[s * 3 + 2]; v.x += u.x; v.y += u.y; v.z += u.z; }
    float local = 1.0f - v.z / fmaxf(sqrtf(v.x) * sqrtf(v.y), EPS);

    #pragma unroll
    for (int off = 32; off > 0; off >>= 1) local += __shfl_down(local, off);
    __shared__ float ws4[4];
    __shared__ int is_last;
    if ((threadIdx.x & 63) == 0) ws4[threadIdx.x >> 6] = local;
    __syncthreads();
    if (threadIdx.x == 0) {
        part[blockIdx.x] = ws4[0] + ws4[1] + ws4[2] + ws4[3];
        __threadfence();                            // release partial
        is_last = (atomicAdd(ticket, 1) == 63);
    }
    __syncthreads();
    if (is_last && threadIdx.x < 64) {
        __threadfence();                            // acquire
        // atomic-read (RMW at device coherence point; safe across XCDs)
        float pv = atomicAdd(&part[threadIdx.x], 0.0f);
        #pragma unroll
        for (int off = 32; off > 0; off >>= 1) pv += __shfl_down(pv, off);
        if (threadIdx.x == 0) out[0] = pv / (float)NSEG;  // fixed-order: deterministic
    }
}

extern "C" void kernel_launch(void* const* d_in, const int* in_sizes, int n_in,
                              void* d_out, int out_size, void* d_ws, size_t ws_size,
                              hipStream_t stream) {
    const float4* p = (const float4*)d_in[0];
    const float4* t = (const float4*)d_in[1];
    const int*    s = (const int*)d_in[2];
    const int n = in_sizes[0];

    // workspace layout (16B-aligned pieces)
    int*    start  = (int*)d_ws;                              // 16385 ints
    float4* wb     = (float4*)((char*)d_ws + 65552);          // 16384*3 float4 = 768 KB
    float*  part   = (float*)((char*)d_ws + 65552 + 786432);  // 64 floats
    int*    ticket = (int*)((char*)d_ws + 65552 + 786432 + 256);

    bsearch_kernel<<<65, 256, 0, stream>>>(s, start, n);
    seg_main<<<1024, 256, 0, stream>>>(p, t, start, wb, ticket);
    fin_fused<<<64, 256, 0, stream>>>(wb, part, ticket, (float*)d_out);
}